// Round 1
// baseline (129.123 us; speedup 1.0000x reference)
//
#include <hip/hip_runtime.h>
#include <hip/hip_bf16.h>

#define BB 32
#define LL 100
#define DD 200      // MEM
#define KIN 360
#define NP (BB*LL)  // 3200
#define RNUM 40
#define LT 13

__device__ __forceinline__ void fma4(float4& a, const float4& w, float s) {
    a.x = fmaf(w.x, s, a.x);
    a.y = fmaf(w.y, s, a.y);
    a.z = fmaf(w.z, s, a.z);
    a.w = fmaf(w.w, s, a.w);
}

// ---------------- prep: denom reciprocal + mask output ----------------
__global__ __launch_bounds__(256) void prep_kernel(const int* __restrict__ adj,
                                                   float* __restrict__ invd,
                                                   float* __restrict__ mask_out) {
    int t = blockIdx.x * 256 + threadIdx.x;
    if (t >= NP) return;
    int b = t / LL, l = t % LL;
    // row count: adj[b,l,:] != 0   (per-lane streaming int4)
    const int4* row = (const int4*)(adj + (size_t)(b * LL + l) * LL);
    int rc = 0;
    #pragma unroll
    for (int i = 0; i < LL / 4; ++i) {
        int4 a = row[i];
        rc += (a.x != 0) + (a.y != 0) + (a.z != 0) + (a.w != 0);
    }
    // col count: adj[b,:,l] != 0   (coalesced across lanes)
    const int* base = adj + (size_t)b * LL * LL + l;
    int cc = 0;
    for (int m = 0; m < LL; ++m) cc += (base[(size_t)m * LL] != 0);
    invd[t] = 1.0f / (float)(rc + 1);
    mask_out[t] = (rc + cc == 0) ? 1.0f : 0.0f;
}

// ---------------- transpose Wp, W0, W1 ----------------
__global__ __launch_bounds__(256) void transpose_kernel(const float* __restrict__ Wp,
                                                        const float* __restrict__ W0,
                                                        const float* __restrict__ W1,
                                                        float* __restrict__ WpT,
                                                        float* __restrict__ W0T,
                                                        float* __restrict__ W1T) {
    int t = blockIdx.x * 256 + threadIdx.x;
    if (t < DD * KIN) {
        int o = t / KIN, k = t % KIN;
        WpT[k * DD + o] = Wp[t];
    } else if (t < DD * KIN + DD * DD) {
        int i = t - DD * KIN;
        int o = i / DD, d = i % DD;
        W0T[d * DD + o] = W0[i];
    } else if (t < DD * KIN + 2 * DD * DD) {
        int i = t - DD * KIN - DD * DD;
        int o = i / DD, d = i % DD;
        W1T[d * DD + o] = W1[i];
    }
}

// ---------------- embedding gather + concat -> embs[3200][360] ----------------
__global__ __launch_bounds__(256) void embed_kernel(const int* __restrict__ words,
                                                    const int* __restrict__ pos,
                                                    const int* __restrict__ ner,
                                                    const float* __restrict__ emb,
                                                    const float* __restrict__ pose,
                                                    const float* __restrict__ nere,
                                                    float* __restrict__ embs) {
    int t = blockIdx.x * 256 + threadIdx.x;  // < NP*KIN = 1,152,000 (exact grid)
    int p = t / KIN, j = t % KIN;
    float v;
    if (j < 300)      v = emb[(size_t)words[p] * 300 + j];
    else if (j < 330) v = pose[pos[p] * 30 + (j - 300)];
    else              v = nere[ner[p] * 30 + (j - 330)];
    embs[t] = v;
}

// ---------------- Ax + x -> S   (the deprel-gathered aggregation) ----------------
// grid: (8 l-tiles, 32 batches). Wave lg owns l = lg + 4*i. Lanes = d-quads.
__global__ __launch_bounds__(256) void ax_kernel(const float* __restrict__ x,
                                                 const int* __restrict__ adj,
                                                 const float* __restrict__ deprel,
                                                 float* __restrict__ S) {
    __shared__ float4 deps[RNUM * 50];       // 32000 B
    __shared__ float4 xs[32 * 50];           // 25600 B
    __shared__ unsigned adjp[LT * 25];       // 1300 B
    int b = blockIdx.y, tile = blockIdx.x;
    int l0 = tile * LT;
    int lcnt = min(LT, LL - l0);
    int t = threadIdx.x;

    // stage deprel table (row 0 is zeros per reference padding_idx)
    for (int i = t; i < RNUM * 50; i += 256) deps[i] = ((const float4*)deprel)[i];
    // byte-pack adj rows for this tile: values < 40 fit in u8
    for (int i = t; i < lcnt * 25; i += 256) {
        int li = i / 25, mg = i % 25;
        int4 a = ((const int4*)(adj + (size_t)((b * LL + l0 + li) * LL)))[mg];
        adjp[i] = (unsigned)a.x | ((unsigned)a.y << 8) | ((unsigned)a.z << 16) | ((unsigned)a.w << 24);
    }
    __syncthreads();

    int lane = t & 63;
    int lg = t >> 6;           // wave id 0..3
    bool act = lane < 50;
    int dq = lane;             // d-quad index

    float4 acc[4];
    #pragma unroll
    for (int i = 0; i < 4; ++i) acc[i] = make_float4(0.f, 0.f, 0.f, 0.f);

    for (int mc = 0; mc < LL; mc += 32) {
        int mcnt = min(32, LL - mc);
        __syncthreads();
        for (int i = t; i < mcnt * 50; i += 256) {
            int mm = i / 50, q = i % 50;
            xs[i] = ((const float4*)x)[(size_t)(b * LL + mc + mm) * 50 + q];
        }
        __syncthreads();
        if (act) {
            for (int mg = 0; mg < mcnt; mg += 4) {
                int gm = (mc + mg) >> 2;
                unsigned ap[4];
                #pragma unroll
                for (int i = 0; i < 4; ++i) {
                    int li = lg + 4 * i;
                    ap[i] = (li < lcnt) ? adjp[li * 25 + gm] : 0u;  // r=0 -> zero row
                }
                #pragma unroll
                for (int mm = 0; mm < 4; ++mm) {
                    float4 xv = xs[(mg + mm) * 50 + dq];
                    #pragma unroll
                    for (int i = 0; i < 4; ++i) {
                        unsigned r = (ap[i] >> (mm * 8)) & 0xffu;
                        float4 dv = deps[r * 50 + dq];
                        acc[i].x = fmaf(dv.x, xv.x, acc[i].x);
                        acc[i].y = fmaf(dv.y, xv.y, acc[i].y);
                        acc[i].z = fmaf(dv.z, xv.z, acc[i].z);
                        acc[i].w = fmaf(dv.w, xv.w, acc[i].w);
                    }
                }
            }
        }
    }
    if (act) {
        #pragma unroll
        for (int i = 0; i < 4; ++i) {
            int li = lg + 4 * i;
            if (li < lcnt) {
                size_t p = (size_t)(b * LL + l0 + li);
                float4 xr = ((const float4*)x)[p * 50 + dq];
                float4 s;
                s.x = acc[i].x + xr.x; s.y = acc[i].y + xr.y;
                s.z = acc[i].z + xr.z; s.w = acc[i].w + xr.w;
                ((float4*)S)[p * 50 + dq] = s;
            }
        }
    }
}

// ---------------- GEMV: out[p][o] = post( in[p][:] @ WT[:,o] ) ----------------
// activations via wave-uniform s_load (SGPR operand of v_fmac); WT coalesced b128.
__global__ __launch_bounds__(256) void gemv_kernel(const float* __restrict__ in,
                                                   const float* __restrict__ wt,
                                                   const float* __restrict__ bias,
                                                   const float* __restrict__ invd,
                                                   float* __restrict__ out,
                                                   int K, float bmult, int relu) {
    int t = threadIdx.x;
    int lane = t & 63;
    int pg = __builtin_amdgcn_readfirstlane(t >> 6);      // wave id, forced SGPR
    int pbase = blockIdx.x * 16 + pg * 4;                 // 4 positions per wave
    int oq = lane;
    bool act = lane < 50;
    int oqc = act ? oq : 49;                              // clamp to stay in-bounds

    const float4* r0 = (const float4*)(in + (size_t)(pbase + 0) * K);
    const float4* r1 = (const float4*)(in + (size_t)(pbase + 1) * K);
    const float4* r2 = (const float4*)(in + (size_t)(pbase + 2) * K);
    const float4* r3 = (const float4*)(in + (size_t)(pbase + 3) * K);
    const float4* wt4 = (const float4*)wt;

    float4 a0 = make_float4(0.f, 0.f, 0.f, 0.f), a1 = a0, a2 = a0, a3 = a0;

    int KQ = K >> 2;
    for (int kq = 0; kq < KQ; ++kq) {
        float4 w0 = wt4[(size_t)(4 * kq + 0) * 50 + oqc];
        float4 w1 = wt4[(size_t)(4 * kq + 1) * 50 + oqc];
        float4 w2 = wt4[(size_t)(4 * kq + 2) * 50 + oqc];
        float4 w3 = wt4[(size_t)(4 * kq + 3) * 50 + oqc];
        float4 s0 = r0[kq], s1 = r1[kq], s2 = r2[kq], s3 = r3[kq];
        fma4(a0, w0, s0.x); fma4(a0, w1, s0.y); fma4(a0, w2, s0.z); fma4(a0, w3, s0.w);
        fma4(a1, w0, s1.x); fma4(a1, w1, s1.y); fma4(a1, w2, s1.z); fma4(a1, w3, s1.w);
        fma4(a2, w0, s2.x); fma4(a2, w1, s2.y); fma4(a2, w2, s2.z); fma4(a2, w3, s2.w);
        fma4(a3, w0, s3.x); fma4(a3, w1, s3.y); fma4(a3, w2, s3.z); fma4(a3, w3, s3.w);
    }
    if (act) {
        float4 bb = ((const float4*)bias)[oq];
        float4 av[4] = {a0, a1, a2, a3};
        #pragma unroll
        for (int j = 0; j < 4; ++j) {
            int p = pbase + j;
            float scale = invd ? invd[p] : 1.0f;
            float4 v;
            v.x = (av[j].x + bmult * bb.x) * scale;
            v.y = (av[j].y + bmult * bb.y) * scale;
            v.z = (av[j].z + bmult * bb.z) * scale;
            v.w = (av[j].w + bmult * bb.w) * scale;
            if (relu) {
                v.x = fmaxf(v.x, 0.f); v.y = fmaxf(v.y, 0.f);
                v.z = fmaxf(v.z, 0.f); v.w = fmaxf(v.w, 0.f);
            }
            ((float4*)out)[(size_t)p * 50 + oq] = v;
        }
    }
}

extern "C" void kernel_launch(void* const* d_in, const int* in_sizes, int n_in,
                              void* d_out, int out_size, void* d_ws, size_t ws_size,
                              hipStream_t stream) {
    const int*   adj   = (const int*)d_in[0];
    const int*   words = (const int*)d_in[1];
    const int*   pos   = (const int*)d_in[2];
    const int*   ner   = (const int*)d_in[3];
    const float* emb   = (const float*)d_in[4];
    const float* pose  = (const float*)d_in[5];
    const float* nere  = (const float*)d_in[6];
    const float* dep   = (const float*)d_in[7];
    const float* Wp    = (const float*)d_in[8];
    const float* bp    = (const float*)d_in[9];
    const float* W0    = (const float*)d_in[10];
    const float* b0    = (const float*)d_in[11];
    const float* W1    = (const float*)d_in[12];
    const float* b1    = (const float*)d_in[13];
    float* out = (float*)d_out;
    float* ws  = (float*)d_ws;

    // workspace layout (floats); S overlays embs (embs dead after proj GEMV)
    float* embs = ws;                    // 1,152,000
    float* S    = ws;                    //   640,000 (overlay)
    float* xA   = ws + 1152000;          //   640,000
    float* xB   = ws + 1792000;          //   640,000
    float* WpT  = ws + 2432000;          //    72,000
    float* W0T  = ws + 2504000;          //    40,000
    float* W1T  = ws + 2544000;          //    40,000
    float* invd = ws + 2584000;          //     3,200

    prep_kernel<<<(NP + 255) / 256, 256, 0, stream>>>(adj, invd, out + NP * DD);
    transpose_kernel<<<(DD * KIN + 2 * DD * DD + 255) / 256, 256, 0, stream>>>(
        Wp, W0, W1, WpT, W0T, W1T);
    embed_kernel<<<(NP * KIN) / 256, 256, 0, stream>>>(words, pos, ner, emb, pose, nere, embs);
    gemv_kernel<<<NP / 16, 256, 0, stream>>>(embs, WpT, bp, nullptr, xA, KIN, 1.0f, 0);

    ax_kernel<<<dim3(8, BB), 256, 0, stream>>>(xA, adj, dep, S);
    gemv_kernel<<<NP / 16, 256, 0, stream>>>(S, W0T, b0, invd, xB, DD, 2.0f, 1);

    ax_kernel<<<dim3(8, BB), 256, 0, stream>>>(xB, adj, dep, S);
    gemv_kernel<<<NP / 16, 256, 0, stream>>>(S, W1T, b1, invd, out, DD, 2.0f, 1);
}

// Round 2
// 115.103 us; speedup vs baseline: 1.1218x; 1.1218x over previous
//
#include <hip/hip_runtime.h>
#include <hip/hip_bf16.h>

#define BB 32
#define LL 100
#define DD 200      // MEM
#define KIN 360
#define NP (BB*LL)  // 3200
#define RNUM 40
#define LT 13
#define NT 8        // l-tiles of 13 (last = 9)

__device__ __forceinline__ void fma4(float4& a, const float4& w, float s) {
    a.x = fmaf(w.x, s, a.x);
    a.y = fmaf(w.y, s, a.y);
    a.z = fmaf(w.z, s, a.z);
    a.w = fmaf(w.w, s, a.w);
}
// RTNE f32 -> bf16 (low 16 bits of result)
__device__ __forceinline__ unsigned bf16rn(float f) {
    unsigned u = __float_as_uint(f);
    return (u + 0x7fffu + ((u >> 16) & 1u)) >> 16;
}
__device__ __forceinline__ unsigned pk2(float a, float b) {
    return bf16rn(a) | (bf16rn(b) << 16);
}
__device__ __forceinline__ float lo16(unsigned u) { return __uint_as_float(u << 16); }
__device__ __forceinline__ float hi16(unsigned u) { return __uint_as_float(u & 0xffff0000u); }

// ---------------- kernel A: prep (invd, mask) + weight transposes ----------------
__global__ __launch_bounds__(256) void prep_transpose_kernel(
        const int* __restrict__ adj,
        const float* __restrict__ Wp, const float* __restrict__ W0, const float* __restrict__ W1,
        float* __restrict__ WpT, float* __restrict__ W0T, float* __restrict__ W1T,
        float* __restrict__ invd, float* __restrict__ mask_out) {
    int bid = blockIdx.x, tid = threadIdx.x;
    if (bid < 13) {
        int t = bid * 256 + tid;
        if (t >= NP) return;
        int b = t / LL, l = t % LL;
        const int4* row = (const int4*)(adj + (size_t)(b * LL + l) * LL);
        int rc = 0;
        #pragma unroll
        for (int i = 0; i < LL / 4; ++i) {
            int4 a = row[i];
            rc += (a.x != 0) + (a.y != 0) + (a.z != 0) + (a.w != 0);
        }
        const int* base = adj + (size_t)b * LL * LL + l;
        int cc = 0;
        for (int m = 0; m < LL; ++m) cc += (base[(size_t)m * LL] != 0);
        invd[t] = 1.0f / (float)(rc + 1);
        mask_out[t] = (rc + cc == 0) ? 1.0f : 0.0f;
    } else {
        // transpose: scattered b32 reads, coalesced b128 writes
        int i = (bid - 13) * 256 + tid;   // output quad index
        if (i < 18000) {                  // WpT: [360][200], quad = (k, oq)
            int k = i / 50, o = (i % 50) * 4;
            float4 v;
            v.x = Wp[(size_t)(o + 0) * KIN + k];
            v.y = Wp[(size_t)(o + 1) * KIN + k];
            v.z = Wp[(size_t)(o + 2) * KIN + k];
            v.w = Wp[(size_t)(o + 3) * KIN + k];
            ((float4*)WpT)[i] = v;
        } else if (i < 28000) {           // W0T: [200][200]
            int q = i - 18000;
            int k = q / 50, o = (q % 50) * 4;
            float4 v;
            v.x = W0[(size_t)(o + 0) * DD + k];
            v.y = W0[(size_t)(o + 1) * DD + k];
            v.z = W0[(size_t)(o + 2) * DD + k];
            v.w = W0[(size_t)(o + 3) * DD + k];
            ((float4*)W0T)[q] = v;
        } else if (i < 38000) {           // W1T
            int q = i - 28000;
            int k = q / 50, o = (q % 50) * 4;
            float4 v;
            v.x = W1[(size_t)(o + 0) * DD + k];
            v.y = W1[(size_t)(o + 1) * DD + k];
            v.z = W1[(size_t)(o + 2) * DD + k];
            v.w = W1[(size_t)(o + 3) * DD + k];
            ((float4*)W1T)[q] = v;
        }
    }
}

// ---------------- kernel B: embedding gather -> LDS -> projection GEMV ----------------
__global__ __launch_bounds__(256) void embed_gemv_kernel(
        const int* __restrict__ words, const int* __restrict__ pos, const int* __restrict__ ner,
        const float* __restrict__ emb, const float* __restrict__ pose, const float* __restrict__ nere,
        const float* __restrict__ wpt, const float* __restrict__ bp,
        float* __restrict__ xA) {
    __shared__ float es[16 * KIN];   // 23 KB
    int tid = threadIdx.x;
    int pbase = blockIdx.x * 16;
    for (int idx = tid; idx < 16 * KIN; idx += 256) {
        int row = idx / KIN, j = idx % KIN;
        int p = pbase + row;
        float v;
        if (j < 300)      v = emb[(size_t)words[p] * 300 + j];
        else if (j < 330) v = pose[pos[p] * 30 + (j - 300)];
        else              v = nere[ner[p] * 30 + (j - 330)];
        es[idx] = v;
    }
    __syncthreads();
    int lane = tid & 63;
    int pg = __builtin_amdgcn_readfirstlane(tid >> 6);
    bool act = lane < 50;
    int oq = act ? lane : 49;
    const float4* wt4 = (const float4*)wpt;
    const float4* es4 = (const float4*)es;
    float4 a[4];
    #pragma unroll
    for (int i = 0; i < 4; ++i) a[i] = make_float4(0.f, 0.f, 0.f, 0.f);
    for (int kq = 0; kq < KIN / 4; ++kq) {
        float4 w0 = wt4[(size_t)(4 * kq + 0) * 50 + oq];
        float4 w1 = wt4[(size_t)(4 * kq + 1) * 50 + oq];
        float4 w2 = wt4[(size_t)(4 * kq + 2) * 50 + oq];
        float4 w3 = wt4[(size_t)(4 * kq + 3) * 50 + oq];
        #pragma unroll
        for (int i = 0; i < 4; ++i) {
            float4 s = es4[(pg * 4 + i) * (KIN / 4) + kq];   // wave-uniform broadcast
            fma4(a[i], w0, s.x); fma4(a[i], w1, s.y);
            fma4(a[i], w2, s.z); fma4(a[i], w3, s.w);
        }
    }
    if (act) {
        float4 bb = ((const float4*)bp)[oq];
        #pragma unroll
        for (int i = 0; i < 4; ++i) {
            int p = pbase + pg * 4 + i;
            float4 v;
            v.x = a[i].x + bb.x; v.y = a[i].y + bb.y;
            v.z = a[i].z + bb.z; v.w = a[i].w + bb.w;
            ((float4*)xA)[(size_t)p * 50 + oq] = v;
        }
    }
}

// ---------------- kernel C: fused GCN layer: Ax (bf16 LDS) + residual + GEMV + relu ----------------
__global__ __launch_bounds__(256) void layer_kernel(
        const float* __restrict__ x, const int* __restrict__ adj,
        const float* __restrict__ deprel, const float* __restrict__ wt,
        const float* __restrict__ bias, const float* __restrict__ invd,
        float* __restrict__ out) {
    __shared__ float4  S_lds[LT * 50];      // 10400 B (fp32, exact residual sum)
    __shared__ uint2   deps_b[RNUM * 50];   // 16000 B (bf16 x4)
    __shared__ uint2   xs_b[LL * 50];       // 40000 B (bf16 x4)
    __shared__ unsigned adjp[LT * 25];      //  1300 B
    int b = blockIdx.y, tile = blockIdx.x;
    int l0 = tile * LT;
    int lcnt = min(LT, LL - l0);
    int tid = threadIdx.x;
    const float4* x4 = (const float4*)x;

    for (int i = tid; i < RNUM * 50; i += 256) {
        float4 v = ((const float4*)deprel)[i];
        deps_b[i] = make_uint2(pk2(v.x, v.y), pk2(v.z, v.w));
    }
    for (int i = tid; i < LL * 50; i += 256) {
        float4 v = x4[(size_t)b * LL * 50 + i];
        xs_b[i] = make_uint2(pk2(v.x, v.y), pk2(v.z, v.w));
    }
    for (int i = tid; i < lcnt * 25; i += 256) {
        int li = i / 25, mg = i % 25;
        int4 a = ((const int4*)(adj + (size_t)(b * LL + l0 + li) * LL))[mg];
        adjp[i] = (unsigned)a.x | ((unsigned)a.y << 8) | ((unsigned)a.z << 16) | ((unsigned)a.w << 24);
    }
    __syncthreads();

    int lane = tid & 63;
    int lg = tid >> 6;
    bool act = lane < 50;
    int dq = lane;

    if (act) {
        float4 acc[4];
        #pragma unroll
        for (int i = 0; i < 4; ++i) acc[i] = make_float4(0.f, 0.f, 0.f, 0.f);
        for (int mg = 0; mg < 25; ++mg) {
            unsigned ap[4];
            #pragma unroll
            for (int i = 0; i < 4; ++i) {
                int li = lg + 4 * i;
                ap[i] = (li < lcnt) ? adjp[li * 25 + mg] : 0u;  // r=0 -> zero deprel row
            }
            #pragma unroll
            for (int mm = 0; mm < 4; ++mm) {
                uint2 xq = xs_b[(4 * mg + mm) * 50 + dq];
                float x0 = lo16(xq.x), x1 = hi16(xq.x);
                float x2 = lo16(xq.y), x3 = hi16(xq.y);
                #pragma unroll
                for (int i = 0; i < 4; ++i) {
                    unsigned r = (ap[i] >> (8 * mm)) & 0xffu;
                    uint2 dv = deps_b[r * 50 + dq];
                    acc[i].x = fmaf(lo16(dv.x), x0, acc[i].x);
                    acc[i].y = fmaf(hi16(dv.x), x1, acc[i].y);
                    acc[i].z = fmaf(lo16(dv.y), x2, acc[i].z);
                    acc[i].w = fmaf(hi16(dv.y), x3, acc[i].w);
                }
            }
        }
        #pragma unroll
        for (int i = 0; i < 4; ++i) {
            int li = lg + 4 * i;
            if (li < lcnt) {
                float4 xr = x4[(size_t)(b * LL + l0 + li) * 50 + dq];  // fp32 residual
                float4 s;
                s.x = acc[i].x + xr.x; s.y = acc[i].y + xr.y;
                s.z = acc[i].z + xr.z; s.w = acc[i].w + xr.w;
                S_lds[li * 50 + dq] = s;
            }
        }
    }
    __syncthreads();

    // GEMV: out = relu((S @ W^T + 2b) * invd)
    const float4* wt4 = (const float4*)wt;
    int oq = act ? lane : 49;
    float4 ba[4];
    #pragma unroll
    for (int i = 0; i < 4; ++i) ba[i] = make_float4(0.f, 0.f, 0.f, 0.f);
    for (int kq = 0; kq < DD / 4; ++kq) {
        float4 w0 = wt4[(size_t)(4 * kq + 0) * 50 + oq];
        float4 w1 = wt4[(size_t)(4 * kq + 1) * 50 + oq];
        float4 w2 = wt4[(size_t)(4 * kq + 2) * 50 + oq];
        float4 w3 = wt4[(size_t)(4 * kq + 3) * 50 + oq];
        #pragma unroll
        for (int i = 0; i < 4; ++i) {
            int li = lg + 4 * i;
            int lic = li < lcnt ? li : 0;
            float4 s = S_lds[lic * 50 + kq];   // wave-uniform broadcast
            fma4(ba[i], w0, s.x); fma4(ba[i], w1, s.y);
            fma4(ba[i], w2, s.z); fma4(ba[i], w3, s.w);
        }
    }
    if (act) {
        float4 bb = ((const float4*)bias)[oq];
        #pragma unroll
        for (int i = 0; i < 4; ++i) {
            int li = lg + 4 * i;
            if (li < lcnt) {
                int p = b * LL + l0 + li;
                float sc = invd[p];
                float4 v;
                v.x = fmaxf((ba[i].x + 2.f * bb.x) * sc, 0.f);
                v.y = fmaxf((ba[i].y + 2.f * bb.y) * sc, 0.f);
                v.z = fmaxf((ba[i].z + 2.f * bb.z) * sc, 0.f);
                v.w = fmaxf((ba[i].w + 2.f * bb.w) * sc, 0.f);
                ((float4*)out)[(size_t)p * 50 + oq] = v;
            }
        }
    }
}

extern "C" void kernel_launch(void* const* d_in, const int* in_sizes, int n_in,
                              void* d_out, int out_size, void* d_ws, size_t ws_size,
                              hipStream_t stream) {
    const int*   adj   = (const int*)d_in[0];
    const int*   words = (const int*)d_in[1];
    const int*   pos   = (const int*)d_in[2];
    const int*   ner   = (const int*)d_in[3];
    const float* emb   = (const float*)d_in[4];
    const float* pose  = (const float*)d_in[5];
    const float* nere  = (const float*)d_in[6];
    const float* dep   = (const float*)d_in[7];
    const float* Wp    = (const float*)d_in[8];
    const float* bp    = (const float*)d_in[9];
    const float* W0    = (const float*)d_in[10];
    const float* b0    = (const float*)d_in[11];
    const float* W1    = (const float*)d_in[12];
    const float* b1    = (const float*)d_in[13];
    float* out = (float*)d_out;
    float* ws  = (float*)d_ws;

    float* xA   = ws;                // 640,000
    float* xB   = ws + 640000;       // 640,000
    float* WpT  = ws + 1280000;      //  72,000
    float* W0T  = ws + 1352000;      //  40,000
    float* W1T  = ws + 1392000;      //  40,000
    float* invd = ws + 1432000;      //   3,200

    prep_transpose_kernel<<<162, 256, 0, stream>>>(adj, Wp, W0, W1, WpT, W0T, W1T,
                                                   invd, out + (size_t)NP * DD);
    embed_gemv_kernel<<<NP / 16, 256, 0, stream>>>(words, pos, ner, emb, pose, nere,
                                                   WpT, bp, xA);
    layer_kernel<<<dim3(NT, BB), 256, 0, stream>>>(xA, adj, dep, W0T, b0, invd, xB);
    layer_kernel<<<dim3(NT, BB), 256, 0, stream>>>(xB, adj, dep, W1T, b1, invd, out);
}

// Round 3
// 75.723 us; speedup vs baseline: 1.7052x; 1.5200x over previous
//
#include <hip/hip_runtime.h>
#include <hip/hip_bf16.h>

#define BB 32
#define LL 100
#define DD 200      // MEM
#define KIN 360
#define NP (BB*LL)  // 3200
#define RNUM 40
#define LT 13
#define NT 8        // l-tiles of 13 (last = 9)

__device__ __forceinline__ void fma4(float4& a, const float4& w, float s) {
    a.x = fmaf(w.x, s, a.x);
    a.y = fmaf(w.y, s, a.y);
    a.z = fmaf(w.z, s, a.z);
    a.w = fmaf(w.w, s, a.w);
}
// RTNE f32 -> bf16
__device__ __forceinline__ unsigned bf16rn(float f) {
    unsigned u = __float_as_uint(f);
    return (u + 0x7fffu + ((u >> 16) & 1u)) >> 16;
}
__device__ __forceinline__ unsigned pk2(float a, float b) {
    return bf16rn(a) | (bf16rn(b) << 16);
}
__device__ __forceinline__ float lo16(unsigned u) { return __uint_as_float(u << 16); }
__device__ __forceinline__ float hi16(unsigned u) { return __uint_as_float(u & 0xffff0000u); }

// ---------------- kernel A: prep (invd, mask) + weight transposes ----------------
__global__ __launch_bounds__(256) void prep_transpose_kernel(
        const int* __restrict__ adj,
        const float* __restrict__ Wp, const float* __restrict__ W0, const float* __restrict__ W1,
        float* __restrict__ WpT, float* __restrict__ W0T, float* __restrict__ W1T,
        float* __restrict__ invd, float* __restrict__ mask_out) {
    int bid = blockIdx.x, tid = threadIdx.x;
    if (bid < 25) {
        int t = bid * 256 + tid;          // < 6400 exactly
        int half = t & 1;
        int pl = t >> 1;                  // (b,l) id 0..3199
        int b = pl / LL, l = pl % LL;
        // half of row count
        const int4* row = (const int4*)(adj + (size_t)pl * LL);
        int q0 = half ? 13 : 0, q1 = half ? 25 : 13;
        int rc = 0;
        for (int i = q0; i < q1; ++i) {
            int4 a = row[i];
            rc += (a.x != 0) + (a.y != 0) + (a.z != 0) + (a.w != 0);
        }
        // half of col count
        const int* base = adj + (size_t)b * LL * LL + l;
        int cc = 0;
        for (int m = half * 50; m < half * 50 + 50; ++m) cc += (base[(size_t)m * LL] != 0);
        rc += __shfl_xor(rc, 1);
        cc += __shfl_xor(cc, 1);
        if (!half) {
            invd[pl] = 1.0f / (float)(rc + 1);
            mask_out[pl] = (rc + cc == 0) ? 1.0f : 0.0f;
        }
    } else {
        // transposes: coalesced reads (fixed k, lanes span k? no: lanes span quad idx
        // -> consecutive k), b128 writes
        int i = (bid - 25) * 256 + tid;   // output quad index
        if (i < 18000) {                  // WpT: [360][200]
            int k = i / 50, o = (i % 50) * 4;
            float4 v;
            v.x = Wp[(size_t)(o + 0) * KIN + k];
            v.y = Wp[(size_t)(o + 1) * KIN + k];
            v.z = Wp[(size_t)(o + 2) * KIN + k];
            v.w = Wp[(size_t)(o + 3) * KIN + k];
            ((float4*)WpT)[i] = v;
        } else if (i < 28000) {           // W0T: [200][200]
            int q = i - 18000;
            int k = q / 50, o = (q % 50) * 4;
            float4 v;
            v.x = W0[(size_t)(o + 0) * DD + k];
            v.y = W0[(size_t)(o + 1) * DD + k];
            v.z = W0[(size_t)(o + 2) * DD + k];
            v.w = W0[(size_t)(o + 3) * DD + k];
            ((float4*)W0T)[q] = v;
        } else if (i < 38000) {           // W1T
            int q = i - 28000;
            int k = q / 50, o = (q % 50) * 4;
            float4 v;
            v.x = W1[(size_t)(o + 0) * DD + k];
            v.y = W1[(size_t)(o + 1) * DD + k];
            v.z = W1[(size_t)(o + 2) * DD + k];
            v.w = W1[(size_t)(o + 3) * DD + k];
            ((float4*)W1T)[q] = v;
        }
    }
}

// ---------------- kernel B: embed gather + proj GEMV, 4-way K-split ----------------
// 400 blocks x 256 threads. Block = 8 positions; wave w = K-chunk w (quads {0..23,
// 24..47, 48..71, 72..89}); LDS reduce of 4 partials.
__global__ __launch_bounds__(256) void embed_gemv_kernel(
        const int* __restrict__ words, const int* __restrict__ pos, const int* __restrict__ ner,
        const float* __restrict__ emb, const float* __restrict__ pose, const float* __restrict__ nere,
        const float* __restrict__ wpt, const float* __restrict__ bp,
        float* __restrict__ xA) {
    __shared__ float es[8 * KIN];        // 11520 B
    __shared__ float4 red[4 * 8 * 50];   // 25600 B
    int tid = threadIdx.x;
    int pbase = blockIdx.x * 8;

    const float2* emb2  = (const float2*)emb;
    const float2* pose2 = (const float2*)pose;
    const float2* nere2 = (const float2*)nere;
    float2* es2 = (float2*)es;
    for (int idx = tid; idx < 8 * 180; idx += 256) {
        int p = idx / 180, j2 = idx % 180;
        int gp = pbase + p;
        float2 v;
        if (j2 < 150)      v = emb2[(size_t)words[gp] * 150 + j2];
        else if (j2 < 165) v = pose2[pos[gp] * 15 + (j2 - 150)];
        else               v = nere2[ner[gp] * 15 + (j2 - 165)];
        es2[idx] = v;
    }
    __syncthreads();

    int lane = tid & 63, w = tid >> 6;
    bool act = lane < 50;
    int oq = act ? lane : 49;
    int kq0 = w * 24;
    int kqn = (w < 3) ? 24 : 18;
    const float4* wt4 = (const float4*)wpt;
    const float4* es4 = (const float4*)es;

    float4 a[8];
    #pragma unroll
    for (int p = 0; p < 8; ++p) a[p] = make_float4(0.f, 0.f, 0.f, 0.f);

    for (int k = 0; k < kqn; ++k) {
        int kq = kq0 + k;
        float4 w0 = wt4[(size_t)(4 * kq + 0) * 50 + oq];
        float4 w1 = wt4[(size_t)(4 * kq + 1) * 50 + oq];
        float4 w2 = wt4[(size_t)(4 * kq + 2) * 50 + oq];
        float4 w3 = wt4[(size_t)(4 * kq + 3) * 50 + oq];
        #pragma unroll
        for (int p = 0; p < 8; ++p) {
            float4 s = es4[p * 90 + kq];   // wave-uniform broadcast
            fma4(a[p], w0, s.x); fma4(a[p], w1, s.y);
            fma4(a[p], w2, s.z); fma4(a[p], w3, s.w);
        }
    }
    if (act) {
        #pragma unroll
        for (int p = 0; p < 8; ++p) red[w * 400 + p * 50 + oq] = a[p];
    }
    __syncthreads();
    for (int t = tid; t < 400; t += 256) {
        int oq2 = t % 50;
        float4 v0 = red[t], v1 = red[400 + t], v2 = red[800 + t], v3 = red[1200 + t];
        float4 bb = ((const float4*)bp)[oq2];
        float4 v;
        v.x = v0.x + v1.x + v2.x + v3.x + bb.x;
        v.y = v0.y + v1.y + v2.y + v3.y + bb.y;
        v.z = v0.z + v1.z + v2.z + v3.z + bb.z;
        v.w = v0.w + v1.w + v2.w + v3.w + bb.w;
        ((float4*)xA)[(size_t)(pbase + t / 50) * 50 + oq2] = v;
    }
}

// ---------------- kernel C: fused layer, 512 threads, m-split Ax + k-split GEMV ----------------
__global__ __launch_bounds__(512) void layer_kernel(
        const float* __restrict__ x, const int* __restrict__ adj,
        const float* __restrict__ deprel, const float* __restrict__ wt,
        const float* __restrict__ bias, const float* __restrict__ invd,
        float* __restrict__ out) {
    __shared__ uint2 deps_b[RNUM * 50];   // 16000 B (bf16 x4)
    __shared__ unsigned adjp[LT * 25];    //  1300 B
    __shared__ float4 Sh[2 * 650];        // 20800 B (Ax partials; later aliased as GEMV partials)
    __shared__ float4 Sfin[650];          // 10400 B
    int b = blockIdx.y, tile = blockIdx.x;
    int l0 = tile * LT;
    int lcnt = min(LT, LL - l0);
    int tid = threadIdx.x;
    const float4* x4 = (const float4*)x;

    for (int i = tid; i < RNUM * 50; i += 512) {
        float4 v = ((const float4*)deprel)[i];
        deps_b[i] = make_uint2(pk2(v.x, v.y), pk2(v.z, v.w));
    }
    for (int i = tid; i < lcnt * 25; i += 512) {
        int li = i / 25, mg = i % 25;
        int4 a = ((const int4*)(adj + (size_t)(b * LL + l0 + li) * LL))[mg];
        adjp[i] = (unsigned)a.x | ((unsigned)a.y << 8) | ((unsigned)a.z << 16) | ((unsigned)a.w << 24);
    }
    __syncthreads();

    int lane = tid & 63, w = tid >> 6;   // 8 waves
    int lg = w & 3, mh = w >> 2;
    bool act = lane < 50;
    int dq = lane;

    // ---- Ax over m-half ----
    float4 acc[4];
    #pragma unroll
    for (int i = 0; i < 4; ++i) acc[i] = make_float4(0.f, 0.f, 0.f, 0.f);
    if (act) {
        int mg0 = mh ? 13 : 0, mg1 = mh ? 25 : 13;
        for (int mg = mg0; mg < mg1; ++mg) {
            unsigned ap[4];
            #pragma unroll
            for (int i = 0; i < 4; ++i) {
                int li = lg + 4 * i;
                ap[i] = (li < lcnt) ? adjp[li * 25 + mg] : 0u;
            }
            #pragma unroll
            for (int mm = 0; mm < 4; ++mm) {
                float4 xv = x4[(size_t)(b * LL + 4 * mg + mm) * 50 + dq];  // L2 direct
                #pragma unroll
                for (int i = 0; i < 4; ++i) {
                    unsigned r = (ap[i] >> (8 * mm)) & 0xffu;
                    uint2 dv = deps_b[r * 50 + dq];
                    acc[i].x = fmaf(lo16(dv.x), xv.x, acc[i].x);
                    acc[i].y = fmaf(hi16(dv.x), xv.y, acc[i].y);
                    acc[i].z = fmaf(lo16(dv.y), xv.z, acc[i].z);
                    acc[i].w = fmaf(hi16(dv.y), xv.w, acc[i].w);
                }
            }
        }
        #pragma unroll
        for (int i = 0; i < 4; ++i) {
            int li = lg + 4 * i;
            if (li < lcnt) Sh[mh * 650 + li * 50 + dq] = acc[i];
        }
    }
    __syncthreads();

    // ---- reduce halves + fp32 residual ----
    for (int t = tid; t < 650; t += 512) {
        int li = t / 50;
        if (li < lcnt) {
            float4 s0 = Sh[t], s1 = Sh[650 + t];
            float4 xr = x4[(size_t)(b * LL + l0 + li) * 50 + (t % 50)];
            float4 s;
            s.x = s0.x + s1.x + xr.x; s.y = s0.y + s1.y + xr.y;
            s.z = s0.z + s1.z + xr.z; s.w = s0.w + s1.w + xr.w;
            Sfin[t] = s;
        }
    }
    __syncthreads();

    // ---- GEMV over k-half ----
    const float4* wt4 = (const float4*)wt;
    int oq = act ? lane : 49;
    float4 ba[4];
    #pragma unroll
    for (int i = 0; i < 4; ++i) ba[i] = make_float4(0.f, 0.f, 0.f, 0.f);
    for (int k = 0; k < 25; ++k) {
        int kq = mh * 25 + k;
        float4 w0 = wt4[(size_t)(4 * kq + 0) * 50 + oq];
        float4 w1 = wt4[(size_t)(4 * kq + 1) * 50 + oq];
        float4 w2 = wt4[(size_t)(4 * kq + 2) * 50 + oq];
        float4 w3 = wt4[(size_t)(4 * kq + 3) * 50 + oq];
        #pragma unroll
        for (int i = 0; i < 4; ++i) {
            int li = lg + 4 * i;
            int lic = li < lcnt ? li : lcnt - 1;
            float4 s = Sfin[lic * 50 + kq];   // wave-uniform broadcast
            fma4(ba[i], w0, s.x); fma4(ba[i], w1, s.y);
            fma4(ba[i], w2, s.z); fma4(ba[i], w3, s.w);
        }
    }
    // write GEMV partials into Sh region (dead after the reduce-read + barrier)
    if (act) {
        #pragma unroll
        for (int i = 0; i < 4; ++i) {
            int li = lg + 4 * i;
            if (li < lcnt) Sh[mh * 650 + li * 50 + oq] = ba[i];
        }
    }
    __syncthreads();

    for (int t = tid; t < 650; t += 512) {
        int li = t / 50, oq2 = t % 50;
        if (li < lcnt) {
            float4 v0 = Sh[t], v1 = Sh[650 + t];
            float4 bb = ((const float4*)bias)[oq2];
            int p = b * LL + l0 + li;
            float sc = invd[p];
            float4 v;
            v.x = fmaxf((v0.x + v1.x + 2.f * bb.x) * sc, 0.f);
            v.y = fmaxf((v0.y + v1.y + 2.f * bb.y) * sc, 0.f);
            v.z = fmaxf((v0.z + v1.z + 2.f * bb.z) * sc, 0.f);
            v.w = fmaxf((v0.w + v1.w + 2.f * bb.w) * sc, 0.f);
            ((float4*)out)[(size_t)p * 50 + oq2] = v;
        }
    }
}

extern "C" void kernel_launch(void* const* d_in, const int* in_sizes, int n_in,
                              void* d_out, int out_size, void* d_ws, size_t ws_size,
                              hipStream_t stream) {
    const int*   adj   = (const int*)d_in[0];
    const int*   words = (const int*)d_in[1];
    const int*   pos   = (const int*)d_in[2];
    const int*   ner   = (const int*)d_in[3];
    const float* emb   = (const float*)d_in[4];
    const float* pose  = (const float*)d_in[5];
    const float* nere  = (const float*)d_in[6];
    const float* dep   = (const float*)d_in[7];
    const float* Wp    = (const float*)d_in[8];
    const float* bp    = (const float*)d_in[9];
    const float* W0    = (const float*)d_in[10];
    const float* b0    = (const float*)d_in[11];
    const float* W1    = (const float*)d_in[12];
    const float* b1    = (const float*)d_in[13];
    float* out = (float*)d_out;
    float* ws  = (float*)d_ws;

    float* xA   = ws;                // 640,000
    float* xB   = ws + 640000;       // 640,000
    float* WpT  = ws + 1280000;      //  72,000
    float* W0T  = ws + 1352000;      //  40,000
    float* W1T  = ws + 1392000;      //  40,000
    float* invd = ws + 1432000;      //   3,200

    prep_transpose_kernel<<<25 + 149, 256, 0, stream>>>(adj, Wp, W0, W1, WpT, W0T, W1T,
                                                        invd, out + (size_t)NP * DD);
    embed_gemv_kernel<<<NP / 8, 256, 0, stream>>>(words, pos, ner, emb, pose, nere,
                                                  WpT, bp, xA);
    layer_kernel<<<dim3(NT, BB), 512, 0, stream>>>(xA, adj, dep, W0T, b0, invd, xB);
    layer_kernel<<<dim3(NT, BB), 512, 0, stream>>>(xB, adj, dep, W1T, b1, invd, out);
}